// Round 5
// baseline (141.635 us; speedup 1.0000x reference)
//
#include <hip/hip_runtime.h>
#include <math.h>

#define BB 128
#define TT 1024
#define II 128
#define HH 512
#define GG 2048           // 4*H
#define BT (BB*TT)
#define LMAX 10

#define BM 128            // rows per tile
#define BN 128            // gate cols per tile = 32 h-cols x 4 gates
#define KCH 128           // K chunk

typedef unsigned short u16;
typedef __attribute__((ext_vector_type(4))) u16 u16x4;
typedef __attribute__((ext_vector_type(8))) u16 u16x8;
typedef __attribute__((ext_vector_type(8))) short bf16x8;
typedef __attribute__((ext_vector_type(4))) float f32x4;

__device__ __forceinline__ float sigf(float v) { return 1.0f / (1.0f + __expf(-v)); }

__device__ __forceinline__ u16 f2b(float f) {
    unsigned int x = __float_as_uint(f);
    return (u16)((x + 0x7fffu + ((x >> 16) & 1u)) >> 16);   // RNE, finite inputs
}

// level-list geometry: lvl0 cap = CAP0 (runtime), 1:1536, 2:512, 3:256, >=4:128
__host__ __device__ __forceinline__ void lvl_geom(int l, int CAP0, int* off, int* cap) {
    if (l == 0) { *off = 0; *cap = CAP0; return; }
    int o = CAP0;
    if (l == 1) { *off = o; *cap = 1536; return; } o += 1536;
    if (l == 2) { *off = o; *cap = 512;  return; } o += 512;
    if (l == 3) { *off = o; *cap = 256;  return; } o += 256;
    *off = o + (l - 4) * 128; *cap = 128;
}
#define LEVELLIST_EXTRA (1536 + 512 + 256 + 6*128)

__device__ __forceinline__ int block_scan_excl(int* scan, int tid, int v, int* total) {
    scan[tid] = v;
    __syncthreads();
    for (int s = 1; s < 256; s <<= 1) {
        int a = scan[tid];
        int u = (tid >= s) ? scan[tid - s] : 0;
        __syncthreads();
        scan[tid] = a + u;
        __syncthreads();
    }
    int incl = scan[tid];
    *total = scan[255];
    __syncthreads();
    return incl - v;
}

// ---------------------------------------------------------------- k_wcvt
// weights -> bf16; also zero levelCount[0..LMAX-1] and barrier at [LMAX]
__global__ void k_wcvt(const float* __restrict__ Wih, const float* __restrict__ Whh,
                       u16* __restrict__ wihb, u16* __restrict__ whhb,
                       int* __restrict__ levelCount) {
    if (blockIdx.x == 0 && threadIdx.x <= LMAX) levelCount[threadIdx.x] = 0;
    int i = blockIdx.x * 256 + threadIdx.x;
    const int NW = GG * II / 4;
    const int NH = GG * HH / 4;
    if (i < NW) {
        float4 v = ((const float4*)Wih)[i];
        u16x4 u = { f2b(v.x), f2b(v.y), f2b(v.z), f2b(v.w) };
        ((u16x4*)wihb)[i] = u;
    } else if (i < NW + NH) {
        int j = i - NW;
        float4 v = ((const float4*)Whh)[j];
        u16x4 u = { f2b(v.x), f2b(v.y), f2b(v.z), f2b(v.w) };
        ((u16x4*)whhb)[j] = u;
    }
}

// ---------------------------------------------------------------- k_prep
// one block per batch row: mask, word count, gather selection, needed marks,
// chain levels, level lists, slots, x->bf16 conversion, pad-row zeroing.
__global__ __launch_bounds__(256) void k_prep(
    const int* __restrict__ mask, const int* __restrict__ length,
    const float* __restrict__ x, float* __restrict__ wnOut,
    int* __restrict__ levelCount, int2* __restrict__ levelList,
    int* __restrict__ slotOf, u16* __restrict__ xb, float* __restrict__ out,
    int K, int R, int CAP0) {
    __shared__ unsigned char sm[TT];
    __shared__ unsigned char sne[TT];
    __shared__ u16 sgp[TT];
    __shared__ int scan[256];
    __shared__ int cnt[LMAX], cnt2[LMAX], bas[LMAX];
    __shared__ u16 spos[256];
    __shared__ u16 zlist[256];
    __shared__ int zn;

    int b = blockIdx.x, tid = threadIdx.x;
    int len = length[b];
    int t0 = tid * 4;
    if (tid == 0) zn = 0;

    int4 mk = ((const int4*)(mask + (size_t)b * TT))[tid];
    int mraw[4] = { mk.x, mk.y, mk.z, mk.w };
    unsigned char mv[4];
    int lzero = 0;
#pragma unroll
    for (int j = 0; j < 4; ++j) {
        int t = t0 + j;
        unsigned char m = (t == len - 1) ? 1 : ((t == 0) ? 0 : (mraw[j] != 0));
        mv[j] = m;
        sm[t] = m;
        sgp[t] = 0;
        lzero += !m;
    }

    int Z;
    int zbase = block_scan_excl(scan, tid, lzero, &Z);
    int wn = TT - Z;
    if (tid == 0) wnOut[b] = (float)wn;
    int need = K - wn;

    int psel[4];
    int lpad = 0;
    {
        int zb = zbase;
#pragma unroll
        for (int j = 0; j < 4; ++j) {
            int sel = mv[j] | ((Z - zb) <= need ? 1 : 0);
            psel[j] = sel;
            lpad += sel;
            zb += !mv[j];
        }
    }
    int ptot;
    int pbase = block_scan_excl(scan, tid, lpad, &ptot);
    {
        int k = pbase;
#pragma unroll
        for (int j = 0; j < 4; ++j) {
            int t = t0 + j;
            if (psel[j]) {
                sgp[t - 1] = (u16)(k + 1);          // t==0 never selected (K << T)
                if (t - 1 >= len) {                 // source inactive -> zero out row
                    int zi = atomicAdd(&zn, 1);
                    if (zi < 256) zlist[zi] = (u16)k;
                }
                ++k;
            }
        }
    }
    __syncthreads();

    // needed (short forward chain walk) + chain level
    int nev[4], lvlv[4];
    int lne = 0;
#pragma unroll
    for (int j = 0; j < 4; ++j) {
        int t = t0 + j;
        int ne = 0;
        if (t < len) {
            int tt = t;
            ne = sgp[tt] != 0;
            while (!ne && tt + 1 < TT && tt + 1 < len && sm[tt + 1]) { ++tt; ne = sgp[tt] != 0; }
        }
        nev[j] = ne;
        sne[t] = (unsigned char)ne;
        lne += ne;
        int l = 0;
        if (mv[j]) { int tt = t; while (tt >= 0 && sm[tt] && l < LMAX - 1) { ++l; --tt; } }
        lvlv[j] = l;
    }

    int ntot;
    int nbase = block_scan_excl(scan, tid, lne, &ntot);   // syncs inside; sne visible
    {
        int r = nbase;
        int sv[4];
#pragma unroll
        for (int j = 0; j < 4; ++j) {
            if (nev[j]) { sv[j] = b * R + r; if (r < 256) spos[r] = (u16)(t0 + j); }
            else sv[j] = -1;
            r += nev[j];
        }
        *(int4*)(slotOf + (size_t)b * TT + t0) = make_int4(sv[0], sv[1], sv[2], sv[3]);
    }

    if (tid < LMAX) { cnt[tid] = 0; cnt2[tid] = 0; }
    __syncthreads();
#pragma unroll
    for (int j = 0; j < 4; ++j) if (nev[j]) atomicAdd(&cnt[lvlv[j]], 1);
    __syncthreads();
    if (tid < LMAX) bas[tid] = cnt[tid] ? atomicAdd(&levelCount[tid], cnt[tid]) : 0;
    __syncthreads();
#pragma unroll
    for (int j = 0; j < 4; ++j) if (nev[j]) {
        int t = t0 + j;
        int l = lvlv[j];
        int r = atomicAdd(&cnt2[l], 1);
        int off, cap;
        lvl_geom(l, CAP0, &off, &cap);
        int idx = bas[l] + r;
        int pred = (t + 1 < TT) && sm[t + 1] && sne[t + 1];
        unsigned int y = (pred ? 0x80000000u : 0u) | (unsigned int)sgp[t];
        if (idx < cap) levelList[off + idx] = make_int2(b * TT + t, (int)y);
    }
    __syncthreads();

    // ---- merged k_xcvt: x rows of needed slots -> bf16
    int nv = (ntot < 256 ? ntot : 256) * 16;
    for (int idx = tid; idx < nv; idx += 256) {
        int r = idx >> 4, part = idx & 15;
        int t = spos[r];
        const float* src = x + ((size_t)b * TT + t) * II + part * 8;
        float4 v0 = ((const float4*)src)[0];
        float4 v1 = ((const float4*)src)[1];
        u16x8 u = { f2b(v0.x), f2b(v0.y), f2b(v0.z), f2b(v0.w),
                    f2b(v1.x), f2b(v1.y), f2b(v1.z), f2b(v1.w) };
        *(u16x8*)(xb + ((size_t)b * R + r) * II + part * 8) = u;
    }
    // ---- merged k_outzero: zero gather rows with inactive sources
    int znv = zn < 256 ? zn : 256;
    for (int idx = tid; idx < znv * 128; idx += 256) {
        int e = idx >> 7, q = idx & 127;
        ((float4*)(out + ((size_t)b * K + zlist[e]) * HH))[q] = make_float4(0.f, 0.f, 0.f, 0.f);
    }
}

// ---------------------------------------------------------------- level tile (device)
__device__ __forceinline__ void level_tile(
    int lvl, const int2* __restrict__ list, int nrow, int jg,
    const u16* __restrict__ xb, const u16* __restrict__ wihb, const u16* __restrict__ whhb,
    const float* __restrict__ bih, const float* __restrict__ bhh,
    const int* __restrict__ slotOf, u16* __restrict__ hb, float* __restrict__ cbuf,
    float* __restrict__ out, int K,
    u16* As, u16* Bs, int* sSlot, int* sPrev, int* sAux) {
    int tid = threadIdx.x;
    if (tid < BM) {
        int2 e = list[(tid < nrow) ? tid : 0];
        int pos = e.x;
        sSlot[tid] = slotOf[pos];
        sPrev[tid] = (lvl > 0) ? slotOf[pos - 1] : 0;
        unsigned int y = (unsigned int)e.y;
        int grank = (int)(y & 0xFFFFu);
        sAux[tid] = (int)((y & 0x80000000u) | (unsigned int)(grank ? ((pos >> 10) * K + grank) : 0));
    }
    __syncthreads();

    int w = tid >> 6, l = tid & 63;
    f32x4 acc[2][8];
#pragma unroll
    for (int rb = 0; rb < 2; ++rb)
#pragma unroll
        for (int cb = 0; cb < 8; ++cb) acc[rb][cb] = (f32x4)0.f;

    int nch = (lvl > 0) ? 5 : 1;           // K chunks of 128 (x:1, x+h:5)
    for (int kc = 0; kc < nch; ++kc) {
        bool fromX = (kc == 0);
        int row = tid >> 1, half = tid & 1;
        // ---- stage A (128 rows x 128 k bf16)
        {
            const u16* src = (fromX ? (xb + (size_t)sSlot[row] * II)
                                    : (hb + (size_t)sPrev[row] * HH + (kc * KCH - II))) + half * 64;
            int swz = (row & 7) << 4;
#pragma unroll
            for (int i = 0; i < 8; ++i) {
                int e2 = half * 128 + i * 16;
                u16x8 v = *(const u16x8*)(src + i * 8);
                *(u16x8*)((char*)As + row * 256 + (e2 ^ swz)) = v;
            }
        }
        // ---- stage B (128 gate cols x 128 k bf16); col r -> gj = (r>>5)*HH + jg*32 + (r&31)
        {
            int gj = (row >> 5) * HH + jg * 32 + (row & 31);
            const u16* src = (fromX ? (wihb + (size_t)gj * II)
                                    : (whhb + (size_t)gj * HH + (kc * KCH - II))) + half * 64;
            int swz = (row & 7) << 4;
#pragma unroll
            for (int i = 0; i < 8; ++i) {
                int e2 = half * 128 + i * 16;
                u16x8 v = *(const u16x8*)(src + i * 8);
                *(u16x8*)((char*)Bs + row * 256 + (e2 ^ swz)) = v;
            }
        }
        __syncthreads();
#pragma unroll
        for (int s = 0; s < 4; ++s) {
            bf16x8 af[2], bfr[8];
#pragma unroll
            for (int rb = 0; rb < 2; ++rb) {
                int rr = w * 32 + rb * 16 + (l & 15);
                int byte = rr * 256 + ((s * 64 + (l >> 4) * 16) ^ ((rr & 7) << 4));
                af[rb] = *(const bf16x8*)((const char*)As + byte);
            }
#pragma unroll
            for (int cb = 0; cb < 8; ++cb) {
                int rr = cb * 16 + (l & 15);
                int byte = rr * 256 + ((s * 64 + (l >> 4) * 16) ^ ((rr & 7) << 4));
                bfr[cb] = *(const bf16x8*)((const char*)Bs + byte);
            }
#pragma unroll
            for (int rb = 0; rb < 2; ++rb)
#pragma unroll
                for (int cb = 0; cb < 8; ++cb)
                    acc[rb][cb] = __builtin_amdgcn_mfma_f32_16x16x32_bf16(
                        af[rb], bfr[cb], acc[rb][cb], 0, 0, 0);
        }
        __syncthreads();
    }

    // ---- epilogue: lane covers 2 h-cols (h0, h0+16) x 4 gates
    int uu = l & 15;
    int h0 = jg * 32 + uu;
    float b_i[2], b_f[2], b_g[2], b_o[2];
#pragma unroll
    for (int h = 0; h < 2; ++h) {
        int hc = h0 + h * 16;
        b_i[h] = bih[hc] + bhh[hc];
        b_f[h] = bih[HH + hc] + bhh[HH + hc];
        b_g[h] = bih[2 * HH + hc] + bhh[2 * HH + hc];
        b_o[h] = bih[3 * HH + hc] + bhh[3 * HH + hc];
    }
#pragma unroll
    for (int rb = 0; rb < 2; ++rb) {
#pragma unroll
        for (int r = 0; r < 4; ++r) {
            int m = w * 32 + rb * 16 + (l >> 4) * 4 + r;
            if (m < nrow) {
                int aux = sAux[m];
                int oi = aux & 0x7FFFFFFF;
                int sp = sPrev[m];
                int sl = sSlot[m];
#pragma unroll
                for (int h = 0; h < 2; ++h) {
                    int hc = h0 + h * 16;
                    float gi = acc[rb][0 + h][r] + b_i[h];
                    float gf = acc[rb][2 + h][r] + b_f[h];
                    float gg = acc[rb][4 + h][r] + b_g[h];
                    float go = acc[rb][6 + h][r] + b_o[h];
                    float cin = (lvl > 0) ? cbuf[(size_t)sp * HH + hc] : 0.f;
                    float c2 = sigf(gf) * cin + sigf(gi) * tanhf(gg);
                    float h2 = sigf(go) * tanhf(c2);
                    if (oi) out[(size_t)(oi - 1) * HH + hc] = h2;
                    if (aux < 0) {
                        hb[(size_t)sl * HH + hc] = f2b(h2);
                        cbuf[(size_t)sl * HH + hc] = c2;
                    }
                }
            }
        }
    }
    __syncthreads();
}

// ---------------------------------------------------------------- k_level (lvl 0 / 1)
__global__ __launch_bounds__(256) void k_level(
    int lvl, int cap, const int* __restrict__ levelCount, const int2* __restrict__ levelList,
    int listOff,
    const u16* __restrict__ xb, const u16* __restrict__ wihb, const u16* __restrict__ whhb,
    const float* __restrict__ bih, const float* __restrict__ bhh,
    const int* __restrict__ slotOf, u16* __restrict__ hb, float* __restrict__ cbuf,
    float* __restrict__ out, int K) {
    __shared__ u16 As[BM * KCH];
    __shared__ u16 Bs[BN * KCH];
    __shared__ int sSlot[BM], sPrev[BM], sAux[BM];
    int n = levelCount[lvl];
    if (n > cap) n = cap;
    int nt = (n + BM - 1) / BM;
    if ((int)blockIdx.x >= nt) return;
    int base = blockIdx.x * BM;
    level_tile(lvl, levelList + listOff + base, min(BM, n - base), blockIdx.y,
               xb, wihb, whhb, bih, bhh, slotOf, hb, cbuf, out, K,
               As, Bs, sSlot, sPrev, sAux);
}

// ---------------------------------------------------------------- k_tail (levels 2..LMAX-1)
// grid = (1, 16): 16 co-resident blocks; device-scope barrier between levels.
__global__ __launch_bounds__(256) void k_tail(
    int CAP0, const int* __restrict__ levelCount, const int2* __restrict__ levelList,
    const u16* __restrict__ xb, const u16* __restrict__ wihb, const u16* __restrict__ whhb,
    const float* __restrict__ bih, const float* __restrict__ bhh,
    const int* __restrict__ slotOf, u16* __restrict__ hb, float* __restrict__ cbuf,
    float* __restrict__ out, int K, int* __restrict__ bar) {
    __shared__ u16 As[BM * KCH];
    __shared__ u16 Bs[BN * KCH];
    __shared__ int sSlot[BM], sPrev[BM], sAux[BM];
    int jg = blockIdx.y;
    int iter = 0;
    for (int l = 2; l < LMAX; ++l) {
        int off, cap;
        lvl_geom(l, CAP0, &off, &cap);
        int n = levelCount[l];
        if (n > cap) n = cap;
        int nt = (n + BM - 1) / BM;
        for (int mt = 0; mt < nt; ++mt) {
            int base = mt * BM;
            level_tile(l, levelList + off + base, min(BM, n - base), jg,
                       xb, wihb, whhb, bih, bhh, slotOf, hb, cbuf, out, K,
                       As, Bs, sSlot, sPrev, sAux);
        }
        ++iter;
        if (l < LMAX - 1) {
            __threadfence();
            __syncthreads();
            if (threadIdx.x == 0) {
                __hip_atomic_fetch_add(bar, 1, __ATOMIC_RELEASE, __HIP_MEMORY_SCOPE_AGENT);
                int target = 16 * iter;
                while (__hip_atomic_load(bar, __ATOMIC_ACQUIRE, __HIP_MEMORY_SCOPE_AGENT) < target) {
                    __builtin_amdgcn_s_sleep(2);
                }
            }
            __syncthreads();
            __threadfence();
        }
    }
}

// ---------------------------------------------------------------- launch
extern "C" void kernel_launch(void* const* d_in, const int* in_sizes, int n_in,
                              void* d_out, int out_size, void* d_ws, size_t ws_size,
                              hipStream_t stream) {
    const float* x    = (const float*)d_in[0];
    const int* mask   = (const int*)d_in[1];
    const int* length = (const int*)d_in[2];
    const float* Wih  = (const float*)d_in[3];
    const float* Whh  = (const float*)d_in[4];
    const float* bih  = (const float*)d_in[5];
    const float* bhh  = (const float*)d_in[6];
    float* out = (float*)d_out;

    int K = (out_size - BB) / (BB * HH);
    int R = K + 64;
    int SLOTS = BB * R;
    int CAP0 = SLOTS;

    char* basep = (char*)d_ws;
    size_t off = 0;
    auto take = [&](size_t bytes) -> char* {
        off = (off + 255) & ~(size_t)255;
        char* p = basep + off;
        off += bytes;
        return p;
    };
    int* slotOf      = (int*)take((size_t)BT * 4);
    int* levelCount  = (int*)take((LMAX + 1) * 4);
    int2* levelList  = (int2*)take((size_t)(CAP0 + LEVELLIST_EXTRA) * 8);
    u16* xb          = (u16*)take((size_t)SLOTS * II * 2);
    u16* hb          = (u16*)take((size_t)SLOTS * HH * 2);
    float* cbuf      = (float*)take((size_t)SLOTS * HH * 4);
    u16* wihb        = (u16*)take((size_t)GG * II * 2);
    u16* whhb        = (u16*)take((size_t)GG * HH * 2);
    int* bar         = levelCount + LMAX;
    (void)ws_size; (void)in_sizes; (void)n_in;

    k_wcvt<<<(GG * (II + HH) / 4 + 255) / 256, 256, 0, stream>>>(Wih, Whh, wihb, whhb, levelCount);
    k_prep<<<BB, 256, 0, stream>>>(mask, length, x, out + (size_t)BB * K * HH,
                                   levelCount, levelList, slotOf, xb, out, K, R, CAP0);

    // level 0 (K=128, no W_hh) and level 1 as wide-tile MFMA launches
    k_level<<<dim3((CAP0 + BM - 1) / BM, GG / BN), 256, 0, stream>>>(
        0, CAP0, levelCount, levelList, 0,
        xb, wihb, whhb, bih, bhh, slotOf, hb, cbuf, out, K);
    {
        int loff, cap;
        lvl_geom(1, CAP0, &loff, &cap);
        k_level<<<dim3((cap + BM - 1) / BM, GG / BN), 256, 0, stream>>>(
            1, cap, levelCount, levelList, loff,
            xb, wihb, whhb, bih, bhh, slotOf, hb, cbuf, out, K);
    }
    // levels 2..LMAX-1 in one kernel with device barrier
    k_tail<<<dim3(1, GG / BN), 256, 0, stream>>>(
        CAP0, levelCount, levelList,
        xb, wihb, whhb, bih, bhh, slotOf, hb, cbuf, out, K, bar);
}